// Round 5
// baseline (1106.187 us; speedup 1.0000x reference)
//
#include <hip/hip_runtime.h>
#include <stdint.h>
#include <math.h>

#define NN 12288
#define DD 128
#define KTOP 31
#define GB 96            // 96 column tiles of 128
#define TCAND 64         // candidate set >= top-64 by bf16 key (verified margin)
#define CCAP 128         // compaction capacity
#define RPB 16           // rows per block (fused kernel); grid = 768
#define LDEP 16          // per-lane ladder depth (16 streams/row x depth16 = 256 keys/row)
#define KBS 260          // keybuf row stride in u32 (bank-spread pad, 16B-aligned)

typedef __attribute__((ext_vector_type(8))) short bf16x8;
typedef __attribute__((ext_vector_type(4))) float f32x4;

__device__ __forceinline__ unsigned short f2bf(float x) {  // RNE, no NaN in our data
  unsigned int u = __float_as_uint(x);
  u += 0x7fffu + ((u >> 16) & 1u);
  return (unsigned short)(u >> 16);
}

// med3(p, L[i], L[i+1]) == sorted-ladder insert step
__device__ __forceinline__ unsigned umed3(unsigned a, unsigned b, unsigned c) {
  unsigned d;
  asm("v_med3_u32 %0, %1, %2, %3" : "=v"(d) : "v"(a), "v"(b), "v"(c));
  return d;
}

#define PINS(P) { \
  const unsigned p_ = (P); \
  _Pragma("unroll") \
  for (int i_ = 0; i_ < LDEP - 1; ++i_) \
    L[i_] = umed3(p_, L[i_], L[i_ + 1]); \
  L[LDEP - 1] = L[LDEP - 1] > p_ ? L[LDEP - 1] : p_; }

// ---------------- Kernel 0: transpose W1,W2 so mlp reads are coalesced ----------------
__global__ __launch_bounds__(128)
void wtrans_kernel(const float* __restrict__ W1, const float* __restrict__ W2,
                   float* __restrict__ W1T, float* __restrict__ W2T) {
  const int r = blockIdx.x, c = threadIdx.x;
  W1T[(size_t)c * DD + r] = W1[(size_t)r * DD + c];
  W2T[(size_t)c * DD + r] = W2[(size_t)r * DD + c];
}

// ---------------- Kernel 1: MLP (Linear-ReLU-Linear) + L2 normalize, fp64; taps fp64 + bf16 ----------------
__global__ __launch_bounds__(128)
void mlp_norm_kernel(const float* __restrict__ feat,
                     const float* __restrict__ W1T, const float* __restrict__ b1,
                     const float* __restrict__ W2T, const float* __restrict__ b2,
                     double* __restrict__ hn64, unsigned short* __restrict__ hnb) {
  __shared__ double bufA[8][DD];
  __shared__ double bufB[8][DD];
  __shared__ double mnorm[8];
  const int t = threadIdx.x;
  const int row0 = blockIdx.x * 8;

  #pragma unroll
  for (int rr = 0; rr < 8; ++rr)
    bufA[rr][t] = (double)feat[(size_t)(row0 + rr) * DD + t];
  __syncthreads();

  {
    double acc[8] = {0,0,0,0,0,0,0,0};
    for (int k = 0; k < DD; k += 2) {
      double w0 = (double)W1T[(size_t)k * DD + t];
      double w1 = (double)W1T[(size_t)(k + 1) * DD + t];
      #pragma unroll
      for (int rr = 0; rr < 8; ++rr) {
        double2 a2 = *(const double2*)(&bufA[rr][k]);
        acc[rr] = fma(w0, a2.x, acc[rr]);
        acc[rr] = fma(w1, a2.y, acc[rr]);
      }
    }
    double bb = (double)b1[t];
    #pragma unroll
    for (int rr = 0; rr < 8; ++rr)
      bufB[rr][t] = fmax(acc[rr] + bb, 0.0);
  }
  __syncthreads();
  {
    double acc[8] = {0,0,0,0,0,0,0,0};
    for (int k = 0; k < DD; k += 2) {
      double w0 = (double)W2T[(size_t)k * DD + t];
      double w1 = (double)W2T[(size_t)(k + 1) * DD + t];
      #pragma unroll
      for (int rr = 0; rr < 8; ++rr) {
        double2 a2 = *(const double2*)(&bufB[rr][k]);
        acc[rr] = fma(w0, a2.x, acc[rr]);
        acc[rr] = fma(w1, a2.y, acc[rr]);
      }
    }
    double bb = (double)b2[t];
    #pragma unroll
    for (int rr = 0; rr < 8; ++rr)
      bufA[rr][t] = acc[rr] + bb;
  }
  __syncthreads();

  const int lane = t & 63;
  const int w = t >> 6;
  #pragma unroll
  for (int r2 = 0; r2 < 4; ++r2) {
    int rr = w * 4 + r2;
    double x0 = bufA[rr][lane];
    double x1 = bufA[rr][lane + 64];
    double s = x0 * x0 + x1 * x1;
    #pragma unroll
    for (int d = 1; d < 64; d <<= 1)
      s += __shfl_xor(s, d);
    if (lane == 0) mnorm[rr] = fmax(sqrt(s), 1e-12);
  }
  __syncthreads();
  #pragma unroll
  for (int rr = 0; rr < 8; ++rr) {
    double v = bufA[rr][t] / mnorm[rr];
    hn64[(size_t)(row0 + rr) * DD + t] = v;
    hnb[(size_t)(row0 + rr) * DD + t] = f2bf((float)v);
  }
}

// ---------------- Kernel 2 (FUSED): sim + per-row top-select + fp64 rescore + emit ----------------
// R5 restructure: NO VMEM stores inside the tile loop. gfx950 has a single
// in-order vmcnt for loads AND stores, so the R4 in-loop NT zero-stores forced
// every tile's MFMA waitcnt to drain the previous tile's stores to HBM
// (~9.5K cyc/tile of hidden serialization — the 482us mystery). Order now:
//   tile loop (loads+MFMA+ladder) -> selection/rescore tail (results parked
//   in LDS) -> 192 back-to-back NT zero-stores -> one vmcnt(0) -> scatter.
__global__ __launch_bounds__(256)
void fused_kernel(const unsigned short* __restrict__ hnb,
                  const double* __restrict__ hn64,
                  float* __restrict__ out) {
  __shared__ unsigned keybuf[RPB][KBS];   // 16 rows x 256 keys (+pad) = 16.6 KB
  __shared__ unsigned scand[4][CCAP];
  __shared__ double cres[4][CCAP];
  __shared__ float outv[RPB][KTOP];       // parked top-31 values per row
  __shared__ int   outc[RPB][KTOP];       // parked top-31 cols per row
  const int t = threadIdx.x, lane = t & 63, wv = t >> 6;
  const int m = lane & 15, quad = lane >> 4;
  const int row0 = blockIdx.x * RPB;

  // A fragments (block's 16 rows), register-resident across the whole loop.
  bf16x8 afrag[4];
  #pragma unroll
  for (int kc = 0; kc < 4; ++kc)
    afrag[kc] = *(const bf16x8*)(hnb + (size_t)(row0 + m) * DD + kc * 32 + quad * 8);

  unsigned L[LDEP];
  #pragma unroll
  for (int i = 0; i < LDEP; ++i) L[i] = 0;

  for (int tile = 0; tile < GB; ++tile) {
    const int cb = tile * 128 + wv * 32;
    f32x4 acc0 = {0.0f, 0.0f, 0.0f, 0.0f};
    f32x4 acc1 = {0.0f, 0.0f, 0.0f, 0.0f};
    #pragma unroll
    for (int kc = 0; kc < 4; ++kc) {
      bf16x8 b0 = *(const bf16x8*)(hnb + (size_t)(cb + m) * DD + kc * 32 + quad * 8);
      bf16x8 b1 = *(const bf16x8*)(hnb + (size_t)(cb + 16 + m) * DD + kc * 32 + quad * 8);
      acc0 = __builtin_amdgcn_mfma_f32_16x16x32_bf16(b0, afrag[kc], acc0, 0, 0, 0);
      acc1 = __builtin_amdgcn_mfma_f32_16x16x32_bf16(b1, afrag[kc], acc1, 0, 0, 0);
    }
    // ladder update: lane owns row row0+m; scores at cols cb+quad*4+r (+16)
    #pragma unroll
    for (int r = 0; r < 4; ++r) {
      {
        unsigned bf = f2bf(acc0[r]);
        unsigned s = (bf & 0x8000u) ? 0u : bf;   // clamp negatives to rank 0
        unsigned p = (s << 16) | (unsigned)(cb + quad * 4 + r);
        PINS(p)
      }
      {
        unsigned bf = f2bf(acc1[r]);
        unsigned s = (bf & 0x8000u) ? 0u : bf;
        unsigned p = (s << 16) | (unsigned)(cb + 16 + quad * 4 + r);
        PINS(p)
      }
    }
  }

  // dump ladders: row m, stream id wv*4+quad
  #pragma unroll
  for (int d = 0; d < LDEP; ++d)
    keybuf[m][(wv * 4 + quad) * LDEP + d] = L[d];
  __syncthreads();

  // per-row: threshold(>=64) select + coalesced fp64 rescore + top-31 -> park in LDS
  for (int ii = 0; ii < 4; ++ii) {
    const int lr = wv * 4 + ii;          // local row (wave owns 4)
    const int grow = row0 + lr;          // global row
    uint4 kk = *(const uint4*)(&keybuf[lr][lane * 4]);
    unsigned k4[4] = {kk.x, kk.y, kk.z, kk.w};

    unsigned lo = 0, hi = 0xFFFFu;
    while (lo < hi) {
      unsigned mid = (lo + hi + 1) >> 1;
      int c = 0;
      #pragma unroll
      for (int i = 0; i < 4; ++i) c += (int)((k4[i] >> 16) >= mid);
      #pragma unroll
      for (int d = 1; d < 64; d <<= 1) c += __shfl_xor(c, d);
      if (c >= TCAND) lo = mid; else hi = mid - 1;
    }
    const unsigned thr = lo;

    int cl = 0;
    #pragma unroll
    for (int i = 0; i < 4; ++i) cl += (int)((k4[i] >> 16) >= thr);
    int pre = cl;
    #pragma unroll
    for (int d = 1; d < 64; d <<= 1) {
      int y = __shfl_up(pre, d);
      if (lane >= d) pre += y;
    }
    const int total = __shfl(pre, 63);
    const int nc = total < CCAP ? total : CCAP;
    int slot = pre - cl;
    #pragma unroll
    for (int i = 0; i < 4; ++i) {
      if ((k4[i] >> 16) >= thr) {
        if (slot < CCAP) scand[wv][slot] = k4[i];
        ++slot;
      }
    }
    // same-wave LDS producer->consumer: compiler inserts lgkmcnt

    const double* arow = hn64 + (size_t)grow * DD;
    const int hl = lane >> 5;
    const int kl = (lane & 31) * 4;
    const double a0 = arow[kl], a1 = arow[kl + 1], a2 = arow[kl + 2], a3 = arow[kl + 3];
    const int ng = (nc + 1) >> 1;
    for (int g = 0; g < ng; ++g) {
      const int ci = 2 * g + hl;
      double partial = 0.0;
      if (ci < nc) {
        const int col = (int)(scand[wv][ci] & 0xFFFFu);
        const double* brow = hn64 + (size_t)col * DD + kl;
        double2 b01 = *(const double2*)(brow);
        double2 b23 = *(const double2*)(brow + 2);
        partial = fma(a0, b01.x, fma(a1, b01.y, fma(a2, b23.x, a3 * b23.y)));
      }
      #pragma unroll
      for (int d = 1; d < 32; d <<= 1)
        partial += __shfl_xor(partial, d);
      if ((lane & 31) == 0 && ci < nc) cres[wv][ci] = partial;
    }
    double rv0 = -1.0e300, rv1 = -1.0e300;
    int rc0 = 0x7fffffff, rc1 = 0x7fffffff;
    if (lane < nc)      { rv0 = cres[wv][lane];      rc0 = (int)(scand[wv][lane] & 0xFFFFu); }
    if (lane + 64 < nc) { rv1 = cres[wv][lane + 64]; rc1 = (int)(scand[wv][lane + 64] & 0xFFFFu); }

    for (int itk = 0; itk < KTOP; ++itk) {
      bool f = (rv0 > rv1) || (rv0 == rv1 && rc0 < rc1);
      double bv = f ? rv0 : rv1;
      int bc = f ? rc0 : rc1;
      #pragma unroll
      for (int d = 1; d < 64; d <<= 1) {
        double ov = __shfl_xor(bv, d);
        int    oc = __shfl_xor(bc, d);
        bool tk = (ov > bv) || (ov == bv && oc < bc);
        bv = tk ? ov : bv;
        bc = tk ? oc : bc;
      }
      if (lane == itk) {
        outv[lr][itk] = (float)fmax(bv, 0.0);
        outc[lr][itk] = bc;
      }
      if (rv0 == bv && rc0 == bc) rv0 = -1.0e300;
      else if (rv1 == bv && rc1 == bc) rv1 = -1.0e300;
    }
  }

  // zero this wave's 4 rows (192 KB, back-to-back NT stores; retire overlaps
  // other blocks' compute on the same CU), then one drain, then scatter.
  f32x4* outz = (f32x4*)(out + (size_t)(row0 + wv * 4) * NN);
  const f32x4 z = {0.0f, 0.0f, 0.0f, 0.0f};
  #pragma unroll 8
  for (int i = 0; i < 192; ++i)
    __builtin_nontemporal_store(z, &outz[i * 64 + lane]);
  asm volatile("s_waitcnt vmcnt(0)" ::: "memory");
  #pragma unroll
  for (int ii = 0; ii < 4; ++ii) {
    const int lr = wv * 4 + ii;
    if (lane < KTOP)
      out[(size_t)(row0 + lr) * NN + outc[lr][lane]] = outv[lr][lane];
  }
}

extern "C" void kernel_launch(void* const* d_in, const int* in_sizes, int n_in,
                              void* d_out, int out_size, void* d_ws, size_t ws_size,
                              hipStream_t stream) {
  const float* feat = (const float*)d_in[0];
  const float* W1 = (const float*)d_in[1];
  const float* b1 = (const float*)d_in[2];
  const float* W2 = (const float*)d_in[3];
  const float* b2 = (const float*)d_in[4];
  float* out = (float*)d_out;

  // ws: hn64 (12.6 MB) | hnb bf16 (3.1 MB) | W1T,W2T (128 KB)
  double* hn64 = (double*)d_ws;
  unsigned short* hnb = (unsigned short*)(hn64 + (size_t)NN * DD);
  float* W1T = (float*)(hnb + (size_t)NN * DD);
  float* W2T = W1T + DD * DD;

  wtrans_kernel<<<DD, DD, 0, stream>>>(W1, W2, W1T, W2T);
  mlp_norm_kernel<<<NN / 8, 128, 0, stream>>>(feat, W1T, b1, W2T, b2, hn64, hnb);
  fused_kernel<<<NN / RPB, 256, 0, stream>>>(hnb, hn64, out);
}

// Round 6
// 947.048 us; speedup vs baseline: 1.1680x; 1.1680x over previous
//
#include <hip/hip_runtime.h>
#include <stdint.h>
#include <math.h>

#define NN 12288
#define DD 128
#define KTOP 31
#define TCAND 64         // candidate set >= top-64 by bf16 key (verified margin)
#define CCAP 128         // compaction capacity
#define RPB 16           // rows per block; grid = 768
#define WPB 8            // waves per block (512 threads)
#define LDEP 14          // ladder depth; 32 streams x 14 = 448 keys/row
#define NSTREAM 32       // WPB * 4 quads
#define KPR (NSTREAM * LDEP)   // 448 keys per row
#define KPL (KPR / 64)         // 7 keys per lane
#define ITERS 48         // column iterations: 12288 / (WPB*32)

typedef __attribute__((ext_vector_type(8))) short bf16x8;
typedef __attribute__((ext_vector_type(4))) float f32x4;

__device__ __forceinline__ unsigned short f2bf(float x) {  // RNE, no NaN in our data
  unsigned int u = __float_as_uint(x);
  u += 0x7fffu + ((u >> 16) & 1u);
  return (unsigned short)(u >> 16);
}

// med3(p, L[i], L[i+1]) == sorted-ladder insert step
__device__ __forceinline__ unsigned umed3(unsigned a, unsigned b, unsigned c) {
  unsigned d;
  asm("v_med3_u32 %0, %1, %2, %3" : "=v"(d) : "v"(a), "v"(b), "v"(c));
  return d;
}

#define PINS(P) { \
  const unsigned p_ = (P); \
  _Pragma("unroll") \
  for (int i_ = 0; i_ < LDEP - 1; ++i_) \
    L[i_] = umed3(p_, L[i_], L[i_ + 1]); \
  L[LDEP - 1] = L[LDEP - 1] > p_ ? L[LDEP - 1] : p_; }

// ---------------- Kernel 0: transpose W1,W2 so mlp reads are coalesced ----------------
__global__ __launch_bounds__(128)
void wtrans_kernel(const float* __restrict__ W1, const float* __restrict__ W2,
                   float* __restrict__ W1T, float* __restrict__ W2T) {
  const int r = blockIdx.x, c = threadIdx.x;
  W1T[(size_t)c * DD + r] = W1[(size_t)r * DD + c];
  W2T[(size_t)c * DD + r] = W2[(size_t)r * DD + c];
}

// ---------------- Kernel 1: MLP (Linear-ReLU-Linear) + L2 normalize, fp64; taps fp64 + bf16 ----------------
__global__ __launch_bounds__(128)
void mlp_norm_kernel(const float* __restrict__ feat,
                     const float* __restrict__ W1T, const float* __restrict__ b1,
                     const float* __restrict__ W2T, const float* __restrict__ b2,
                     double* __restrict__ hn64, unsigned short* __restrict__ hnb) {
  __shared__ double bufA[8][DD];
  __shared__ double bufB[8][DD];
  __shared__ double mnorm[8];
  const int t = threadIdx.x;
  const int row0 = blockIdx.x * 8;

  #pragma unroll
  for (int rr = 0; rr < 8; ++rr)
    bufA[rr][t] = (double)feat[(size_t)(row0 + rr) * DD + t];
  __syncthreads();

  {
    double acc[8] = {0,0,0,0,0,0,0,0};
    for (int k = 0; k < DD; k += 2) {
      double w0 = (double)W1T[(size_t)k * DD + t];
      double w1 = (double)W1T[(size_t)(k + 1) * DD + t];
      #pragma unroll
      for (int rr = 0; rr < 8; ++rr) {
        double2 a2 = *(const double2*)(&bufA[rr][k]);
        acc[rr] = fma(w0, a2.x, acc[rr]);
        acc[rr] = fma(w1, a2.y, acc[rr]);
      }
    }
    double bb = (double)b1[t];
    #pragma unroll
    for (int rr = 0; rr < 8; ++rr)
      bufB[rr][t] = fmax(acc[rr] + bb, 0.0);
  }
  __syncthreads();
  {
    double acc[8] = {0,0,0,0,0,0,0,0};
    for (int k = 0; k < DD; k += 2) {
      double w0 = (double)W2T[(size_t)k * DD + t];
      double w1 = (double)W2T[(size_t)(k + 1) * DD + t];
      #pragma unroll
      for (int rr = 0; rr < 8; ++rr) {
        double2 a2 = *(const double2*)(&bufB[rr][k]);
        acc[rr] = fma(w0, a2.x, acc[rr]);
        acc[rr] = fma(w1, a2.y, acc[rr]);
      }
    }
    double bb = (double)b2[t];
    #pragma unroll
    for (int rr = 0; rr < 8; ++rr)
      bufA[rr][t] = acc[rr] + bb;
  }
  __syncthreads();

  const int lane = t & 63;
  const int w = t >> 6;
  #pragma unroll
  for (int r2 = 0; r2 < 4; ++r2) {
    int rr = w * 4 + r2;
    double x0 = bufA[rr][lane];
    double x1 = bufA[rr][lane + 64];
    double s = x0 * x0 + x1 * x1;
    #pragma unroll
    for (int d = 1; d < 64; d <<= 1)
      s += __shfl_xor(s, d);
    if (lane == 0) mnorm[rr] = fmax(sqrt(s), 1e-12);
  }
  __syncthreads();
  #pragma unroll
  for (int rr = 0; rr < 8; ++rr) {
    double v = bufA[rr][t] / mnorm[rr];
    hn64[(size_t)(row0 + rr) * DD + t] = v;
    hnb[(size_t)(row0 + rr) * DD + t] = f2bf((float)v);
  }
}

// ---------------- Kernel 2 (FUSED): sim + per-row top-select + fp64 rescore + emit ----------------
// R6: 8 waves/block (each scans 1/8 of columns) -> 6144 waves = 6/SIMD (~75%
// occupancy vs R5's 32%); launch_bounds(512,6) lifts the VGPR squeeze (was 40);
// in-loop NT zero stores RESTORED (R4 vs R5 A/B: in-loop is 95us cheaper).
// Ladder: 32 streams/row x depth-14 = 448 keys/row (margin for fp64-top-31
// survival ~1e-2 misses/run, safer than the R4/R5 config that passed twice).
__global__ __launch_bounds__(512, 6)
void fused_kernel(const unsigned short* __restrict__ hnb,
                  const double* __restrict__ hn64,
                  float* __restrict__ out) {
  __shared__ unsigned keybuf[RPB][KPR + 1];   // 16 x 449 u32 = 28.7 KB
  __shared__ unsigned scand[WPB][CCAP];       // 4 KB
  __shared__ double cres[WPB][CCAP];          // 8 KB
  __shared__ float outv[RPB][KTOP];           // 2 KB
  __shared__ int   outc[RPB][KTOP];           // 2 KB
  const int t = threadIdx.x, lane = t & 63, wv = t >> 6;
  const int m = lane & 15, quad = lane >> 4;
  const int row0 = blockIdx.x * RPB;

  // A fragments (block's 16 rows), register-resident.
  bf16x8 afrag[4];
  #pragma unroll
  for (int kc = 0; kc < 4; ++kc)
    afrag[kc] = *(const bf16x8*)(hnb + (size_t)(row0 + m) * DD + kc * 32 + quad * 8);

  unsigned L[LDEP];
  #pragma unroll
  for (int i = 0; i < LDEP; ++i) L[i] = 0;

  // wave-private zero region: rows row0 + wv*2 .. +2 (6144 f32x4)
  f32x4* outz = (f32x4*)(out + (size_t)(row0 + wv * 2) * NN);
  const f32x4 z = {0.0f, 0.0f, 0.0f, 0.0f};

  for (int it = 0; it < ITERS; ++it) {
    const int cb = it * (WPB * 32) + wv * 32;
    f32x4 acc0 = {0.0f, 0.0f, 0.0f, 0.0f};
    f32x4 acc1 = {0.0f, 0.0f, 0.0f, 0.0f};
    #pragma unroll
    for (int kc = 0; kc < 4; ++kc) {
      bf16x8 b0 = *(const bf16x8*)(hnb + (size_t)(cb + m) * DD + kc * 32 + quad * 8);
      bf16x8 b1 = *(const bf16x8*)(hnb + (size_t)(cb + 16 + m) * DD + kc * 32 + quad * 8);
      acc0 = __builtin_amdgcn_mfma_f32_16x16x32_bf16(b0, afrag[kc], acc0, 0, 0, 0);
      acc1 = __builtin_amdgcn_mfma_f32_16x16x32_bf16(b1, afrag[kc], acc1, 0, 0, 0);
    }
    // in-loop NT zero stores (retire overlaps compute — R4-proven free)
    __builtin_nontemporal_store(z, &outz[it * 128 + lane]);
    __builtin_nontemporal_store(z, &outz[it * 128 + 64 + lane]);
    // ladder update: lane owns row row0+m; scores at cols cb+quad*4+r (+16)
    #pragma unroll
    for (int r = 0; r < 4; ++r) {
      {
        unsigned bf = f2bf(acc0[r]);
        unsigned s = (bf & 0x8000u) ? 0u : bf;   // clamp negatives to rank 0
        unsigned p = (s << 16) | (unsigned)(cb + quad * 4 + r);
        PINS(p)
      }
      {
        unsigned bf = f2bf(acc1[r]);
        unsigned s = (bf & 0x8000u) ? 0u : bf;
        unsigned p = (s << 16) | (unsigned)(cb + 16 + quad * 4 + r);
        PINS(p)
      }
    }
  }

  // dump ladders: row m, stream id wv*4+quad
  #pragma unroll
  for (int d = 0; d < LDEP; ++d)
    keybuf[m][(wv * 4 + quad) * LDEP + d] = L[d];
  __syncthreads();

  // per-row (2 rows per wave): threshold select + coalesced fp64 rescore + top-31
  for (int ii = 0; ii < 2; ++ii) {
    const int lr = wv * 2 + ii;
    const int grow = row0 + lr;
    unsigned k7[KPL];
    #pragma unroll
    for (int i = 0; i < KPL; ++i)
      k7[i] = keybuf[lr][lane * KPL + i];

    unsigned lo = 0, hi = 0xFFFFu;
    while (lo < hi) {
      unsigned mid = (lo + hi + 1) >> 1;
      int c = 0;
      #pragma unroll
      for (int i = 0; i < KPL; ++i) c += (int)((k7[i] >> 16) >= mid);
      #pragma unroll
      for (int d = 1; d < 64; d <<= 1) c += __shfl_xor(c, d);
      if (c >= TCAND) lo = mid; else hi = mid - 1;
    }
    const unsigned thr = lo;

    int cl = 0;
    #pragma unroll
    for (int i = 0; i < KPL; ++i) cl += (int)((k7[i] >> 16) >= thr);
    int pre = cl;
    #pragma unroll
    for (int d = 1; d < 64; d <<= 1) {
      int y = __shfl_up(pre, d);
      if (lane >= d) pre += y;
    }
    const int total = __shfl(pre, 63);
    const int nc = total < CCAP ? total : CCAP;
    int slot = pre - cl;
    #pragma unroll
    for (int i = 0; i < KPL; ++i) {
      if ((k7[i] >> 16) >= thr) {
        if (slot < CCAP) scand[wv][slot] = k7[i];
        ++slot;
      }
    }
    // same-wave LDS producer->consumer: compiler inserts lgkmcnt

    const double* arow = hn64 + (size_t)grow * DD;
    const int hl = lane >> 5;
    const int kl = (lane & 31) * 4;
    const double a0 = arow[kl], a1 = arow[kl + 1], a2 = arow[kl + 2], a3 = arow[kl + 3];
    const int ng = (nc + 1) >> 1;
    for (int g = 0; g < ng; ++g) {
      const int ci = 2 * g + hl;
      double partial = 0.0;
      if (ci < nc) {
        const int col = (int)(scand[wv][ci] & 0xFFFFu);
        const double* brow = hn64 + (size_t)col * DD + kl;
        double2 b01 = *(const double2*)(brow);
        double2 b23 = *(const double2*)(brow + 2);
        partial = fma(a0, b01.x, fma(a1, b01.y, fma(a2, b23.x, a3 * b23.y)));
      }
      #pragma unroll
      for (int d = 1; d < 32; d <<= 1)
        partial += __shfl_xor(partial, d);
      if ((lane & 31) == 0 && ci < nc) cres[wv][ci] = partial;
    }
    double rv0 = -1.0e300, rv1 = -1.0e300;
    int rc0 = 0x7fffffff, rc1 = 0x7fffffff;
    if (lane < nc)      { rv0 = cres[wv][lane];      rc0 = (int)(scand[wv][lane] & 0xFFFFu); }
    if (lane + 64 < nc) { rv1 = cres[wv][lane + 64]; rc1 = (int)(scand[wv][lane + 64] & 0xFFFFu); }

    for (int itk = 0; itk < KTOP; ++itk) {
      bool f = (rv0 > rv1) || (rv0 == rv1 && rc0 < rc1);
      double bv = f ? rv0 : rv1;
      int bc = f ? rc0 : rc1;
      #pragma unroll
      for (int d = 1; d < 64; d <<= 1) {
        double ov = __shfl_xor(bv, d);
        int    oc = __shfl_xor(bc, d);
        bool tk = (ov > bv) || (ov == bv && oc < bc);
        bv = tk ? ov : bv;
        bc = tk ? oc : bc;
      }
      if (lane == itk) {
        outv[lr][itk] = (float)fmax(bv, 0.0);
        outc[lr][itk] = bc;
      }
      if (rv0 == bv && rc0 == bc) rv0 = -1.0e300;
      else if (rv1 == bv && rc1 == bc) rv1 = -1.0e300;
    }
  }

  // drain this wave's remaining zero stores, then scatter its 2 rows from LDS
  asm volatile("s_waitcnt vmcnt(0)" ::: "memory");
  #pragma unroll
  for (int ii = 0; ii < 2; ++ii) {
    const int lr = wv * 2 + ii;
    if (lane < KTOP)
      out[(size_t)(row0 + lr) * NN + outc[lr][lane]] = outv[lr][lane];
  }
}

extern "C" void kernel_launch(void* const* d_in, const int* in_sizes, int n_in,
                              void* d_out, int out_size, void* d_ws, size_t ws_size,
                              hipStream_t stream) {
  const float* feat = (const float*)d_in[0];
  const float* W1 = (const float*)d_in[1];
  const float* b1 = (const float*)d_in[2];
  const float* W2 = (const float*)d_in[3];
  const float* b2 = (const float*)d_in[4];
  float* out = (float*)d_out;

  // ws: hn64 (12.6 MB) | hnb bf16 (3.1 MB) | W1T,W2T (128 KB)
  double* hn64 = (double*)d_ws;
  unsigned short* hnb = (unsigned short*)(hn64 + (size_t)NN * DD);
  float* W1T = (float*)(hnb + (size_t)NN * DD);
  float* W2T = W1T + DD * DD;

  wtrans_kernel<<<DD, DD, 0, stream>>>(W1, W2, W1T, W2T);
  mlp_norm_kernel<<<NN / 8, 128, 0, stream>>>(feat, W1T, b1, W2T, b2, hn64, hnb);
  fused_kernel<<<NN / RPB, 512, 0, stream>>>(hnb, hn64, out);
}